// Round 7
// baseline (1027.252 us; speedup 1.0000x reference)
//
#include <hip/hip_runtime.h>
#include <hip/hip_bf16.h>
#include <stdint.h>

// ProjSolver R7: fused step (znew cols [0,2048) + resid cols [2048,3072)).
// Block 256 thr / 4 waves, tile 128x64. In-block split-K: waves 0-1 compute
// K[0,1024) (stream 0), waves 2-3 K[1024,2048) (stream 1), each wave a 64x64
// quadrant (4x4 16x16x32 bf16 frags). K-loop: 32 iterations x 32-K per stream
// (R6 bug was kk<16 -> half of K missing; R5 had the same class of bug).
// Double-buffered LDS per stream (48 KB -> 3 blocks/CU = 12 waves/CU).
// XOR chunk swizzle (global-side kc = slot ^ ((row>>1)&3), mirrored at
// ds_read) -> 0 bank conflicts (verified R5). Explicit s_waitcnt vmcnt(0)
// before each K-loop barrier (DMA completion is per-wave; insurance).
// Epilogue: waves 2-3 dump partial accs to LDS (32 KB = sizeof(sA), exact),
// waves 0-1 add + store znew (bias+relu) or reduce resid max -> atomicMax;
// last resid block (ticket) updates done/iters in-kernel.

typedef __hip_bfloat16 bf16;
typedef __attribute__((ext_vector_type(8))) short short8;
typedef __attribute__((ext_vector_type(4))) float f32x4;

#define N_DIM 2048
#define K_DIM 2048
#define MRES  1024
#define FREE_NUM 1024
#define NTOT (2048*2048)
#define F_TOL 1e-6f
#define MAX_ITER 16
#define NRB 256   // resid blocks: 16 x-tiles * 16 y-tiles

__device__ __forceinline__ void async_cp16(const void* g, void* l) {
  __builtin_amdgcn_global_load_lds(
      (const __attribute__((address_space(1))) unsigned int*)g,
      (__attribute__((address_space(3))) unsigned int*)l, 16, 0, 0);
}

__device__ __forceinline__ void drain_dma() {
  asm volatile("s_waitcnt vmcnt(0)" ::: "memory");
}

// flags: [0]=res max bits, [1]=done, [2]=iters, [3]=ticket
__global__ void k_init(unsigned* f) { f[0]=0u; f[1]=0u; f[2]=0u; f[3]=0u; }

__global__ __launch_bounds__(256) void k_cast(
    const float* __restrict__ in, bf16* __restrict__ o, int n)
{
  int i = (blockIdx.x * 256 + threadIdx.x) * 4;
  if (i < n) {
    float4 v = *(const float4*)(in + i);
    o[i + 0] = __float2bfloat16(v.x);
    o[i + 1] = __float2bfloat16(v.y);
    o[i + 2] = __float2bfloat16(v.z);
    o[i + 3] = __float2bfloat16(v.w);
  }
}

__global__ __launch_bounds__(256) void k_bias(
    const float* __restrict__ b, const float* __restrict__ Wb,
    float* __restrict__ bias)
{
  const int j = blockIdx.x;
  const int tid = threadIdx.x;
  float s = 0.f;
  for (int m = tid; m < MRES; m += 256)
    s += b[m] * Wb[(size_t)j * MRES + m];
#pragma unroll
  for (int off = 32; off > 0; off >>= 1) s += __shfl_xor(s, off);
  __shared__ float red[4];
  const int w = tid >> 6, l = tid & 63;
  if (l == 0) red[w] = s;
  __syncthreads();
  if (tid == 0) bias[j] = red[0] + red[1] + red[2] + red[3];
}

// ---------------- fused step: C = Zin @ [Wz; A]^T ----------------------------
__global__ __launch_bounds__(256, 3) void k_step(
    const bf16* __restrict__ Zin, const bf16* __restrict__ Wzb,
    const bf16* __restrict__ Ab, const float* __restrict__ bias,
    const float* __restrict__ bvec, bf16* __restrict__ Zout,
    unsigned* __restrict__ flags, int consume)
{
  __shared__ __align__(16) short sA[2][2][128 * 32];  // [stream][buf] 4x8 KB
  __shared__ __align__(16) short sB[2][2][64 * 32];   // [stream][buf] 4x4 KB
  __shared__ unsigned s_done;
  __shared__ float wred[4];
  __shared__ unsigned s_last;

  const int tid = threadIdx.x;
  if (tid == 0) s_done = flags[1];
  const int w = tid >> 6, l = tid & 63;     // 4 waves
  const int q = l >> 4, lm = l & 15;
  const int sw = (lm >> 1) & 3;             // read-side swizzle key
  const int khalf = w >> 1, wrow = w & 1;   // k-stream, row-half
  const int rowBase = blockIdx.y * 128;
  const int colBase = blockIdx.x * 64;
  const bool isZ = colBase < N_DIM;
  __syncthreads();
  const unsigned done0 = s_done;

  float mx = 0.f;
  f32x4 acc[4][4];
  if (!done0) {
    const bf16* Bp = isZ ? (Wzb + (size_t)colBase * K_DIM)
                         : (Ab + (size_t)(colBase - N_DIM) * K_DIM);
    f32x4 zero4 = {0.f, 0.f, 0.f, 0.f};
#pragma unroll
    for (int i = 0; i < 4; i++)
#pragma unroll
      for (int j = 0; j < 4; j++) acc[i][j] = zero4;

    // Stage both streams' K-tile kk into buffer p. 6 DMAs/thread.
    // Stream s covers k = s*1024 + kk*32, kk in [0,32)  -> full K union.
    // Chunk c: row=c>>2, slot=c&3, global chunk kc = slot ^ ((row>>1)&3).
    auto stage = [&](int kk, int p) {
#pragma unroll
      for (int s = 0; s < 2; s++) {
        const int ks = s * 1024 + kk * 32;
        short* sAp = sA[s][p];
        short* sBp = sB[s][p];
#pragma unroll
        for (int r = 0; r < 2; r++) {            // A: 512 chunks, 2/thread
          int c = tid + 256 * r;
          int row = c >> 2, sl = c & 3;
          int kc = sl ^ ((row >> 1) & 3);
          async_cp16(Zin + (size_t)(rowBase + row) * K_DIM + ks + kc * 8,
                     sAp + c * 8);
        }
        {                                         // B: 256 chunks, 1/thread
          int c = tid;
          int row = c >> 2, sl = c & 3;
          int kc = sl ^ ((row >> 1) & 3);
          async_cp16(Bp + (size_t)row * K_DIM + ks + kc * 8, sBp + c * 8);
        }
      }
    };

    stage(0, 0);
#pragma unroll 2
    for (int kk = 0; kk < 32; kk++) {             // 32 x 32-K per stream
      const int cur = kk & 1;
      drain_dma();                 // own-wave DMA drain; barrier orders waves
      __syncthreads();             // publishes tile `cur` to all waves
      if (kk < 31) stage(kk + 1, cur ^ 1);
      const short* sAc = sA[khalf][cur];
      const short* sBc = sB[khalf][cur];
      short8 af[4], bfr[4];
#pragma unroll
      for (int mr = 0; mr < 4; mr++) {
        int R = wrow * 64 + mr * 16 + lm;
        af[mr] = *(const short8*)(sAc + (R * 4 + (q ^ sw)) * 8);
      }
#pragma unroll
      for (int nc = 0; nc < 4; nc++) {
        int Rb = nc * 16 + lm;
        bfr[nc] = *(const short8*)(sBc + (Rb * 4 + (q ^ sw)) * 8);
      }
#pragma unroll
      for (int mr = 0; mr < 4; mr++)
#pragma unroll
        for (int nc = 0; nc < 4; nc++)
          acc[mr][nc] = __builtin_amdgcn_mfma_f32_16x16x32_bf16(
              af[mr], bfr[nc], acc[mr][nc], 0, 0, 0);
    }

    // ---- split-K reduction: waves 2-3 dump partials, waves 0-1 add ----
    float* fs = (float*)sA;        // 32 KB scratch == sizeof(sA), exact fit
    drain_dma();
    __syncthreads();               // all K-loop LDS reads done before reuse
    if (khalf == 1) {
      float* dst = fs + ((size_t)(wrow * 64 + l)) * 64;
#pragma unroll
      for (int mr = 0; mr < 4; mr++)
#pragma unroll
        for (int nc = 0; nc < 4; nc++)
          *(f32x4*)(dst + (mr * 4 + nc) * 4) = acc[mr][nc];
    }
    __syncthreads();
    if (khalf == 0) {
      const float* src = fs + ((size_t)(wrow * 64 + l)) * 64;
#pragma unroll
      for (int mr = 0; mr < 4; mr++)
#pragma unroll
        for (int nc = 0; nc < 4; nc++)
          acc[mr][nc] += *(const f32x4*)(src + (mr * 4 + nc) * 4);
    }

    if (khalf == 0) {
      if (isZ) {
#pragma unroll
        for (int mr = 0; mr < 4; mr++) {
#pragma unroll
          for (int nc = 0; nc < 4; nc++) {
            int gc = colBase + nc * 16 + lm;
            int gr0 = rowBase + wrow * 64 + mr * 16 + q * 4;
            float bv = bias[gc];
#pragma unroll
            for (int r = 0; r < 4; r++) {
              float v = acc[mr][nc][r] + bv;
              if (gc >= FREE_NUM) v = fmaxf(v, 0.f);
              Zout[(size_t)(gr0 + r) * N_DIM + gc] = __float2bfloat16(v);
            }
          }
        }
      } else {
#pragma unroll
        for (int mr = 0; mr < 4; mr++) {
#pragma unroll
          for (int nc = 0; nc < 4; nc++) {
            int rc = colBase - N_DIM + nc * 16 + lm;
            float bv = bvec[rc];
#pragma unroll
            for (int r = 0; r < 4; r++)
              mx = fmaxf(mx, fabsf(acc[mr][nc][r] - bv));
          }
        }
      }
    }
  }

  if (!isZ) {
#pragma unroll
    for (int off = 32; off > 0; off >>= 1) mx = fmaxf(mx, __shfl_xor(mx, off));
    if (l == 0) wred[w] = mx;     // waves 2-3 contribute 0
    __syncthreads();
    if (tid == 0) {
      if (!done0) {
        float m2 = fmaxf(fmaxf(wred[0], wred[1]), fmaxf(wred[2], wred[3]));
        atomicMax(flags, __float_as_uint(m2));  // values non-negative
      }
      __threadfence();
      unsigned tk = atomicAdd(flags + 3, 1u);
      s_last = (tk == NRB - 1) ? 1u : 0u;
    }
    __syncthreads();
    if (s_last && tid == 0) {
      unsigned rb = atomicMax(flags, 0u);       // coherent read of res max
      float res = __uint_as_float(rb);
      if (consume && flags[1] == 0u) {
        flags[2] += 1u;                          // iters++ for iteration t-1
        if (res <= F_TOL) flags[1] = 1u;         // done latch
      }
      flags[0] = 0u;
      flags[3] = 0u;
      __threadfence();
    }
  }
}

__global__ __launch_bounds__(256) void k_final(
    const bf16* __restrict__ z0, const bf16* __restrict__ z1,
    const unsigned* __restrict__ flags, float* __restrict__ out)
{
  size_t i = (size_t)blockIdx.x * 256 + threadIdx.x;
  unsigned done = flags[1], iters = flags[2];
  const bf16* src = done ? ((iters & 1u) ? z1 : z0) : z0;
  if (i < NTOT) out[i] = __bfloat162float(src[i]);
  else if (i == NTOT) out[i] = (float)(iters + (done ? 0u : 1u) + 1u);
}

// ---------------- launcher ----------------------------------------------------
extern "C" void kernel_launch(void* const* d_in, const int* in_sizes, int n_in,
                              void* d_out, int out_size, void* d_ws, size_t ws_size,
                              hipStream_t stream) {
  const float* z  = (const float*)d_in[0];
  const float* b  = (const float*)d_in[1];
  const float* A  = (const float*)d_in[2];
  const float* Wz = (const float*)d_in[3];
  const float* Wb = (const float*)d_in[4];
  float* out = (float*)d_out;

  // bf16 weights parked in d_out bytes (overwritten by k_final at the end)
  bf16* Wzb = (bf16*)d_out;                 // 8 MB
  bf16* Ab  = Wzb + (size_t)NTOT;           // 4 MB

  char* ws = (char*)d_ws;                   // ~16.01 MB used
  unsigned* flags = (unsigned*)ws;
  float* bias = (float*)(ws + 256);
  bf16* buf0 = (bf16*)(ws + 256 + 2048 * sizeof(float));
  bf16* buf1 = buf0 + (size_t)NTOT;

  k_init<<<1, 1, 0, stream>>>(flags);
  k_cast<<<NTOT / 1024, 256, 0, stream>>>(Wz, Wzb, NTOT);
  k_cast<<<(MRES * N_DIM) / 1024, 256, 0, stream>>>(A, Ab, MRES * N_DIM);
  k_cast<<<NTOT / 1024, 256, 0, stream>>>(z, buf0, NTOT);   // z(0) -> buf0
  k_bias<<<N_DIM, 256, 0, stream>>>(b, Wb, bias);

  for (int t = 1; t <= MAX_ITER; t++) {
    const bf16* in = ((t - 1) & 1) ? buf1 : buf0;   // z(t-1)
    bf16* o = (t & 1) ? buf1 : buf0;                // z(t)
    k_step<<<dim3(48, 16), 256, 0, stream>>>(in, Wzb, Ab, bias, b, o, flags,
                                             (t >= 2) ? 1 : 0);
  }
  k_final<<<(NTOT + 256) / 256 + 1, 256, 0, stream>>>(buf0, buf1, flags, out);
}

// Round 8
// 726.536 us; speedup vs baseline: 1.4139x; 1.4139x over previous
//
#include <hip/hip_runtime.h>
#include <hip/hip_bf16.h>
#include <stdint.h>

// ProjSolver R8: fused step (znew cols [0,2048) + resid cols [2048,3072)).
// Frame = R4: grid 48x16=768 blocks, 128 thr / 2 waves, tile 128x64, each wave
// a 64x64 quadrant (4x4 16x16x32 bf16 frags), full K per wave.
// HYBRID STAGING EXPERIMENT (vs R7's all-DMA): A-tile (16 KB/blk/kk, 2/3 of
// staged bytes) via global_load_dwordx4 -> VGPR -> ds_write_b128 (ordinary
// load path, ~34.5 TB/s L2 ceiling); B-tile stays on global_load_lds DMA
// (~13 TB/s path, measured R5/R7 + m97). If the paths are independent the
// ~48 us staging component drops to ~15-25 us.
// Double-buffered LDS; XOR chunk swizzle (global kc = slot ^ ((row>>1)&3),
// mirrored at ds_read) -> 0 conflicts (verified R5). A-register pipeline:
// loads for kk+2 issued during kk (one full iteration of latency cover, so
// the compiler's vmcnt(0)-at-barrier drain is harmless).
// No split-K (R7 showed 0 benefit; its f32 epilogue caused 2.85M conflict cyc).

typedef __hip_bfloat16 bf16;
typedef __attribute__((ext_vector_type(8))) short short8;
typedef __attribute__((ext_vector_type(4))) float f32x4;

#define N_DIM 2048
#define K_DIM 2048
#define MRES  1024
#define FREE_NUM 1024
#define NTOT (2048*2048)
#define F_TOL 1e-6f
#define MAX_ITER 16
#define NRB 256   // resid blocks: 16 x-tiles * 16 y-tiles

__device__ __forceinline__ void async_cp16(const void* g, void* l) {
  __builtin_amdgcn_global_load_lds(
      (const __attribute__((address_space(1))) unsigned int*)g,
      (__attribute__((address_space(3))) unsigned int*)l, 16, 0, 0);
}

__device__ __forceinline__ void drain_dma() {
  asm volatile("s_waitcnt vmcnt(0)" ::: "memory");
}

// flags: [0]=res max bits, [1]=done, [2]=iters, [3]=ticket
__global__ void k_init(unsigned* f) { f[0]=0u; f[1]=0u; f[2]=0u; f[3]=0u; }

__global__ __launch_bounds__(256) void k_cast(
    const float* __restrict__ in, bf16* __restrict__ o, int n)
{
  int i = (blockIdx.x * 256 + threadIdx.x) * 4;
  if (i < n) {
    float4 v = *(const float4*)(in + i);
    o[i + 0] = __float2bfloat16(v.x);
    o[i + 1] = __float2bfloat16(v.y);
    o[i + 2] = __float2bfloat16(v.z);
    o[i + 3] = __float2bfloat16(v.w);
  }
}

__global__ __launch_bounds__(256) void k_bias(
    const float* __restrict__ b, const float* __restrict__ Wb,
    float* __restrict__ bias)
{
  const int j = blockIdx.x;
  const int tid = threadIdx.x;
  float s = 0.f;
  for (int m = tid; m < MRES; m += 256)
    s += b[m] * Wb[(size_t)j * MRES + m];
#pragma unroll
  for (int off = 32; off > 0; off >>= 1) s += __shfl_xor(s, off);
  __shared__ float red[4];
  const int w = tid >> 6, l = tid & 63;
  if (l == 0) red[w] = s;
  __syncthreads();
  if (tid == 0) bias[j] = red[0] + red[1] + red[2] + red[3];
}

// ---------------- fused step: C = Zin @ [Wz; A]^T ----------------------------
__global__ __launch_bounds__(128, 3) void k_step(
    const bf16* __restrict__ Zin, const bf16* __restrict__ Wzb,
    const bf16* __restrict__ Ab, const float* __restrict__ bias,
    const float* __restrict__ bvec, bf16* __restrict__ Zout,
    unsigned* __restrict__ flags, int consume)
{
  __shared__ __align__(16) short sA[2][128 * 32];   // 2 x 8 KB
  __shared__ __align__(16) short sB[2][64 * 32];    // 2 x 4 KB
  __shared__ unsigned s_done;
  __shared__ float wred[2];
  __shared__ unsigned s_last;

  const int tid = threadIdx.x;
  if (tid == 0) s_done = flags[1];
  const int w = tid >> 6, l = tid & 63;             // 2 waves
  const int q = l >> 4, lm = l & 15;
  const int sw = (lm >> 1) & 3;                     // read-side swizzle key
  const int rowBase = blockIdx.y * 128;
  const int colBase = blockIdx.x * 64;
  const bool isZ = colBase < N_DIM;
  __syncthreads();
  const unsigned done0 = s_done;

  float mx = 0.f;
  if (!done0) {
    const bf16* Bp = isZ ? (Wzb + (size_t)colBase * K_DIM)
                         : (Ab + (size_t)(colBase - N_DIM) * K_DIM);
    f32x4 acc[4][4];
    f32x4 zero4 = {0.f, 0.f, 0.f, 0.f};
#pragma unroll
    for (int i = 0; i < 4; i++)
#pragma unroll
      for (int j = 0; j < 4; j++) acc[i][j] = zero4;

    // A: 512 16B-chunks -> 4/thread (explicit load+ds_write).
    // B: 256 16B-chunks -> 2/thread (DMA).
    // Chunk c: row=c>>2, slot=c&3, global chunk kc = slot ^ ((row>>1)&3).
    const bf16* aptr[4];  int aoff[4];
#pragma unroll
    for (int r = 0; r < 4; r++) {
      int c = tid + 128 * r;
      int row = c >> 2, sl = c & 3;
      int kc = sl ^ ((row >> 1) & 3);
      aptr[r] = Zin + (size_t)(rowBase + row) * K_DIM + kc * 8;
      aoff[r] = c * 8;
    }
    const bf16* bptr[2]; int boff[2];
#pragma unroll
    for (int r = 0; r < 2; r++) {
      int c = tid + 128 * r;
      int row = c >> 2, sl = c & 3;
      int kc = sl ^ ((row >> 1) & 3);
      bptr[r] = Bp + (size_t)row * K_DIM + kc * 8;
      boff[r] = c * 8;
    }

    // Prologue: fill buf0 for kk=0, prefetch A regs for kk=1.
    short8 apipe[4];
#pragma unroll
    for (int r = 0; r < 2; r++) async_cp16(bptr[r], sB[0] + boff[r]);
#pragma unroll
    for (int r = 0; r < 4; r++) apipe[r] = *(const short8*)(aptr[r]);
#pragma unroll
    for (int r = 0; r < 4; r++) *(short8*)(sA[0] + aoff[r]) = apipe[r];
#pragma unroll
    for (int r = 0; r < 4; r++) apipe[r] = *(const short8*)(aptr[r] + 32);

#pragma unroll 2
    for (int kk = 0; kk < 32; kk++) {
      const int cur = kk & 1;
      drain_dma();                 // own-wave B-DMA + A loads complete
      __syncthreads();             // publish buf[cur]
      if (kk < 31) {
        const int nxt = cur ^ 1;
        const int ko = (kk + 1) * 32;
#pragma unroll
        for (int r = 0; r < 2; r++)
          async_cp16(bptr[r] + ko, sB[nxt] + boff[r]);
#pragma unroll
        for (int r = 0; r < 4; r++)
          *(short8*)(sA[nxt] + aoff[r]) = apipe[r];   // A for kk+1
      }
      if (kk < 30) {
        const int ko2 = (kk + 2) * 32;
#pragma unroll
        for (int r = 0; r < 4; r++)
          apipe[r] = *(const short8*)(aptr[r] + ko2); // A for kk+2 in flight
      }
      const short* sAc = sA[cur];
      const short* sBc = sB[cur];
      short8 af[4], bfr[4];
#pragma unroll
      for (int mr = 0; mr < 4; mr++) {
        int R = w * 64 + mr * 16 + lm;
        af[mr] = *(const short8*)(sAc + (R * 4 + (q ^ sw)) * 8);
      }
#pragma unroll
      for (int nc = 0; nc < 4; nc++) {
        int Rb = nc * 16 + lm;
        bfr[nc] = *(const short8*)(sBc + (Rb * 4 + (q ^ sw)) * 8);
      }
#pragma unroll
      for (int mr = 0; mr < 4; mr++)
#pragma unroll
        for (int nc = 0; nc < 4; nc++)
          acc[mr][nc] = __builtin_amdgcn_mfma_f32_16x16x32_bf16(
              af[mr], bfr[nc], acc[mr][nc], 0, 0, 0);
    }

    if (isZ) {
#pragma unroll
      for (int mr = 0; mr < 4; mr++) {
#pragma unroll
        for (int nc = 0; nc < 4; nc++) {
          int gc = colBase + nc * 16 + lm;
          int gr0 = rowBase + w * 64 + mr * 16 + q * 4;
          float bv = bias[gc];
#pragma unroll
          for (int r = 0; r < 4; r++) {
            float v = acc[mr][nc][r] + bv;
            if (gc >= FREE_NUM) v = fmaxf(v, 0.f);
            Zout[(size_t)(gr0 + r) * N_DIM + gc] = __float2bfloat16(v);
          }
        }
      }
    } else {
#pragma unroll
      for (int mr = 0; mr < 4; mr++) {
#pragma unroll
        for (int nc = 0; nc < 4; nc++) {
          int rc = colBase - N_DIM + nc * 16 + lm;
          float bv = bvec[rc];
#pragma unroll
          for (int r = 0; r < 4; r++)
            mx = fmaxf(mx, fabsf(acc[mr][nc][r] - bv));
        }
      }
    }
  }

  if (!isZ) {
#pragma unroll
    for (int off = 32; off > 0; off >>= 1) mx = fmaxf(mx, __shfl_xor(mx, off));
    if (l == 0) wred[w] = mx;
    __syncthreads();
    if (tid == 0) {
      if (!done0) {
        float m2 = fmaxf(wred[0], wred[1]);
        atomicMax(flags, __float_as_uint(m2));  // values non-negative
      }
      __threadfence();
      unsigned tk = atomicAdd(flags + 3, 1u);
      s_last = (tk == NRB - 1) ? 1u : 0u;
    }
    __syncthreads();
    if (s_last && tid == 0) {
      unsigned rb = atomicMax(flags, 0u);       // coherent read of res max
      float res = __uint_as_float(rb);
      if (consume && flags[1] == 0u) {
        flags[2] += 1u;                          // iters++ for iteration t-1
        if (res <= F_TOL) flags[1] = 1u;         // done latch
      }
      flags[0] = 0u;
      flags[3] = 0u;
      __threadfence();
    }
  }
}

__global__ __launch_bounds__(256) void k_final(
    const bf16* __restrict__ z0, const bf16* __restrict__ z1,
    const unsigned* __restrict__ flags, float* __restrict__ out)
{
  size_t i = (size_t)blockIdx.x * 256 + threadIdx.x;
  unsigned done = flags[1], iters = flags[2];
  const bf16* src = done ? ((iters & 1u) ? z1 : z0) : z0;
  if (i < NTOT) out[i] = __bfloat162float(src[i]);
  else if (i == NTOT) out[i] = (float)(iters + (done ? 0u : 1u) + 1u);
}

// ---------------- launcher ----------------------------------------------------
extern "C" void kernel_launch(void* const* d_in, const int* in_sizes, int n_in,
                              void* d_out, int out_size, void* d_ws, size_t ws_size,
                              hipStream_t stream) {
  const float* z  = (const float*)d_in[0];
  const float* b  = (const float*)d_in[1];
  const float* A  = (const float*)d_in[2];
  const float* Wz = (const float*)d_in[3];
  const float* Wb = (const float*)d_in[4];
  float* out = (float*)d_out;

  // bf16 weights parked in d_out bytes (overwritten by k_final at the end)
  bf16* Wzb = (bf16*)d_out;                 // 8 MB
  bf16* Ab  = Wzb + (size_t)NTOT;           // 4 MB

  char* ws = (char*)d_ws;                   // ~16.01 MB used
  unsigned* flags = (unsigned*)ws;
  float* bias = (float*)(ws + 256);
  bf16* buf0 = (bf16*)(ws + 256 + 2048 * sizeof(float));
  bf16* buf1 = buf0 + (size_t)NTOT;

  k_init<<<1, 1, 0, stream>>>(flags);
  k_cast<<<NTOT / 1024, 256, 0, stream>>>(Wz, Wzb, NTOT);
  k_cast<<<(MRES * N_DIM) / 1024, 256, 0, stream>>>(A, Ab, MRES * N_DIM);
  k_cast<<<NTOT / 1024, 256, 0, stream>>>(z, buf0, NTOT);   // z(0) -> buf0
  k_bias<<<N_DIM, 256, 0, stream>>>(b, Wb, bias);

  for (int t = 1; t <= MAX_ITER; t++) {
    const bf16* in = ((t - 1) & 1) ? buf1 : buf0;   // z(t-1)
    bf16* o = (t & 1) ? buf1 : buf0;                // z(t)
    k_step<<<dim3(48, 16), 128, 0, stream>>>(in, Wzb, Ab, bias, b, o, flags,
                                             (t >= 2) ? 1 : 0);
  }
  k_final<<<(NTOT + 256) / 256 + 1, 256, 0, stream>>>(buf0, buf1, flags, out);
}